// Round 1
// baseline (41.398 us; speedup 1.0000x reference)
//
#include <hip/hip_runtime.h>

// Compute the 12 constants of the inverse rigid transform for batch b:
//   R = quat_to_rot(normalize(q));  Rinv = R^T;  tinv = -R^T * t
__device__ __forceinline__ void inv_rigid(const float* __restrict__ dq,
                                          const float* __restrict__ dt,
                                          int b,
                                          float& i00, float& i01, float& i02,
                                          float& i10, float& i11, float& i12,
                                          float& i20, float& i21, float& i22,
                                          float& tix, float& tiy, float& tiz) {
    float qw = dq[b * 4 + 0];
    float qx = dq[b * 4 + 1];
    float qy = dq[b * 4 + 2];
    float qz = dq[b * 4 + 3];
    float inv = 1.0f / sqrtf(qw * qw + qx * qx + qy * qy + qz * qz);
    qw *= inv; qx *= inv; qy *= inv; qz *= inv;

    // Rotation matrix R (row-major)
    float r00 = 1.0f - 2.0f * (qy * qy + qz * qz);
    float r01 = 2.0f * (qx * qy - qw * qz);
    float r02 = 2.0f * (qx * qz + qw * qy);
    float r10 = 2.0f * (qx * qy + qw * qz);
    float r11 = 1.0f - 2.0f * (qx * qx + qz * qz);
    float r12 = 2.0f * (qy * qz - qw * qx);
    float r20 = 2.0f * (qx * qz - qw * qy);
    float r21 = 2.0f * (qy * qz + qw * qx);
    float r22 = 1.0f - 2.0f * (qx * qx + qy * qy);

    // Rinv = R^T
    i00 = r00; i01 = r10; i02 = r20;
    i10 = r01; i11 = r11; i12 = r21;
    i20 = r02; i21 = r12; i22 = r22;

    float tx = dt[b * 3 + 0];
    float ty = dt[b * 3 + 1];
    float tz = dt[b * 3 + 2];
    tix = -(i00 * tx + i01 * ty + i02 * tz);
    tiy = -(i10 * tx + i11 * ty + i12 * tz);
    tiz = -(i20 * tx + i21 * ty + i22 * tz);
}

// Kernel 1: per-batch batch_T_pred = delta_T_inv @ T_mis  (16 x 16 floats)
__global__ void batch_T_kernel(const float* __restrict__ T_mis,
                               const float* __restrict__ dq,
                               const float* __restrict__ dt,
                               float* __restrict__ out_T,
                               int B) {
    int b = threadIdx.x;
    if (b >= B) return;

    float i00, i01, i02, i10, i11, i12, i20, i21, i22, tix, tiy, tiz;
    inv_rigid(dq, dt, b, i00, i01, i02, i10, i11, i12, i20, i21, i22, tix, tiy, tiz);

    const float* T = T_mis + b * 16;
    float* O = out_T + b * 16;

    float Ri[3][3] = {{i00, i01, i02}, {i10, i11, i12}, {i20, i21, i22}};
    float ti[3] = {tix, tiy, tiz};
#pragma unroll
    for (int i = 0; i < 3; ++i) {
#pragma unroll
        for (int k = 0; k < 4; ++k) {
            O[i * 4 + k] = Ri[i][0] * T[0 * 4 + k] + Ri[i][1] * T[1 * 4 + k] +
                           Ri[i][2] * T[2 * 4 + k] + ti[i] * T[3 * 4 + k];
        }
    }
    // bottom row of delta_T_inv is [0,0,0,1] -> last row of product = last row of T
#pragma unroll
    for (int k = 0; k < 4; ++k) O[3 * 4 + k] = T[3 * 4 + k];
}

// Kernel 2: pcd_realigned[b,n,:] = Rinv @ pcd[b,n,:] + tinv
// Each thread handles 4 points = 3 float4 loads + 3 float4 stores (48 B each way).
__global__ void pcd_kernel(const float4* __restrict__ pin,
                           float4* __restrict__ pout,
                           const float* __restrict__ dq,
                           const float* __restrict__ dt,
                           int groups_per_batch,   // N/4
                           int rem_points,         // N%4
                           long long n_per_batch)  // N
{
    int b = blockIdx.y;

    float i00, i01, i02, i10, i11, i12, i20, i21, i22, tix, tiy, tiz;
    inv_rigid(dq, dt, b, i00, i01, i02, i10, i11, i12, i20, i21, i22, tix, tiy, tiz);

    // base index into float4 space for this batch (N*3 floats per batch; 16B-aligned)
    long long base4 = (long long)b * (n_per_batch * 3LL) / 4LL;

    for (long long g = (long long)blockIdx.x * blockDim.x + threadIdx.x;
         g < groups_per_batch;
         g += (long long)gridDim.x * blockDim.x) {
        long long idx = base4 + g * 3LL;
        float4 A = pin[idx];
        float4 Bv = pin[idx + 1];
        float4 C = pin[idx + 2];

        // unpack 4 points
        float x0 = A.x, y0 = A.y, z0 = A.z;
        float x1 = A.w, y1 = Bv.x, z1 = Bv.y;
        float x2 = Bv.z, y2 = Bv.w, z2 = C.x;
        float x3 = C.y, y3 = C.z, z3 = C.w;

        float ox0 = i00 * x0 + i01 * y0 + i02 * z0 + tix;
        float oy0 = i10 * x0 + i11 * y0 + i12 * z0 + tiy;
        float oz0 = i20 * x0 + i21 * y0 + i22 * z0 + tiz;

        float ox1 = i00 * x1 + i01 * y1 + i02 * z1 + tix;
        float oy1 = i10 * x1 + i11 * y1 + i12 * z1 + tiy;
        float oz1 = i20 * x1 + i21 * y1 + i22 * z1 + tiz;

        float ox2 = i00 * x2 + i01 * y2 + i02 * z2 + tix;
        float oy2 = i10 * x2 + i11 * y2 + i12 * z2 + tiy;
        float oz2 = i20 * x2 + i21 * y2 + i22 * z2 + tiz;

        float ox3 = i00 * x3 + i01 * y3 + i02 * z3 + tix;
        float oy3 = i10 * x3 + i11 * y3 + i12 * z3 + tiy;
        float oz3 = i20 * x3 + i21 * y3 + i22 * z3 + tiz;

        float4 OA = make_float4(ox0, oy0, oz0, ox1);
        float4 OB = make_float4(oy1, oz1, ox2, oy2);
        float4 OC = make_float4(oz2, ox3, oy3, oz3);
        pout[idx] = OA;
        pout[idx + 1] = OB;
        pout[idx + 2] = OC;
    }

    // tail: N % 4 leftover points, handled scalar by a few threads of block 0
    if (rem_points > 0 && blockIdx.x == 0 && threadIdx.x < (unsigned)rem_points) {
        long long p = (long long)groups_per_batch * 4LL + threadIdx.x;  // point index
        const float* fin = (const float*)pin;
        float* fout = (float*)pout;
        long long fbase = (long long)b * (n_per_batch * 3LL) + p * 3LL;
        float x = fin[fbase + 0], y = fin[fbase + 1], z = fin[fbase + 2];
        fout[fbase + 0] = i00 * x + i01 * y + i02 * z + tix;
        fout[fbase + 1] = i10 * x + i11 * y + i12 * z + tiy;
        fout[fbase + 2] = i20 * x + i21 * y + i22 * z + tiz;
    }
}

extern "C" void kernel_launch(void* const* d_in, const int* in_sizes, int n_in,
                              void* d_out, int out_size, void* d_ws, size_t ws_size,
                              hipStream_t stream) {
    const float* pcd = (const float*)d_in[0];      // (B, N, 3)
    const float* T_mis = (const float*)d_in[1];    // (B, 4, 4)
    const float* dq = (const float*)d_in[2];       // (B, 4)
    const float* dt = (const float*)d_in[3];       // (B, 3)

    int B = in_sizes[2] / 4;                        // 16
    long long N = (long long)in_sizes[0] / (3LL * B);  // 500000

    float* out_T = (float*)d_out;                  // first B*16 floats
    float* out_pcd = (float*)d_out + (long long)B * 16;  // then B*N*3 floats

    // Kernel 1: tiny per-batch 4x4 work
    batch_T_kernel<<<dim3(1), dim3(64), 0, stream>>>(T_mis, dq, dt, out_T, B);

    // Kernel 2: the big pointwise transform
    int groups = (int)(N / 4);
    int rem = (int)(N % 4);
    int blocks_x = (int)((groups + 255) / 256);
    if (blocks_x < 1) blocks_x = 1;
    dim3 grid(blocks_x, B);
    pcd_kernel<<<grid, dim3(256), 0, stream>>>(
        (const float4*)pcd, (float4*)out_pcd, dq, dt, groups, rem, N);
}

// Round 2
// 39.753 us; speedup vs baseline: 1.0414x; 1.0414x over previous
//
#include <hip/hip_runtime.h>

// Compute the 12 constants of the inverse rigid transform for batch b:
//   R = quat_to_rot(normalize(q));  Rinv = R^T;  tinv = -R^T * t
__device__ __forceinline__ void inv_rigid(const float* __restrict__ dq,
                                          const float* __restrict__ dt,
                                          int b,
                                          float& i00, float& i01, float& i02,
                                          float& i10, float& i11, float& i12,
                                          float& i20, float& i21, float& i22,
                                          float& tix, float& tiy, float& tiz) {
    float qw = dq[b * 4 + 0];
    float qx = dq[b * 4 + 1];
    float qy = dq[b * 4 + 2];
    float qz = dq[b * 4 + 3];
    float inv = 1.0f / sqrtf(qw * qw + qx * qx + qy * qy + qz * qz);
    qw *= inv; qx *= inv; qy *= inv; qz *= inv;

    float r00 = 1.0f - 2.0f * (qy * qy + qz * qz);
    float r01 = 2.0f * (qx * qy - qw * qz);
    float r02 = 2.0f * (qx * qz + qw * qy);
    float r10 = 2.0f * (qx * qy + qw * qz);
    float r11 = 1.0f - 2.0f * (qx * qx + qz * qz);
    float r12 = 2.0f * (qy * qz - qw * qx);
    float r20 = 2.0f * (qx * qz - qw * qy);
    float r21 = 2.0f * (qy * qz + qw * qx);
    float r22 = 1.0f - 2.0f * (qx * qx + qy * qy);

    // Rinv = R^T
    i00 = r00; i01 = r10; i02 = r20;
    i10 = r01; i11 = r11; i12 = r21;
    i20 = r02; i21 = r12; i22 = r22;

    float tx = dt[b * 3 + 0];
    float ty = dt[b * 3 + 1];
    float tz = dt[b * 3 + 2];
    tix = -(i00 * tx + i01 * ty + i02 * tz);
    tiy = -(i10 * tx + i11 * ty + i12 * tz);
    tiz = -(i20 * tx + i21 * ty + i22 * tz);
}

// Fused kernel: fully-coalesced point transform (1 float4 per thread, neighbor
// components via __shfl) + batch_T_pred computed by threads 0..15 of block (0,b).
//
// Output float4 m covers global floats 4m..4m+3; with r = m%3:
//   r==0: point p0=(v.x,v.y,v.z), p1=(v.w, in[m+1].x, in[m+1].y)
//   r==1: p1=(in[m-1].w, v.x, v.y), p2=(v.z, v.w, in[m+1].x)
//   r==2: p2=(in[m-1].z, in[m-1].w, v.x), p3=(v.y,v.z,v.w)
// Only in[m-1].z/.w and in[m+1].x/.y are ever needed -> 4 shuffles.
__global__ void realign_kernel(const float4* __restrict__ pin,
                               float4* __restrict__ pout,
                               const float* __restrict__ T_mis,
                               const float* __restrict__ dq,
                               const float* __restrict__ dt,
                               float* __restrict__ out_T,
                               int m4_per_batch)  // = N*3/4 float4s per batch
{
    int b = blockIdx.y;

    float i00, i01, i02, i10, i11, i12, i20, i21, i22, tix, tiy, tiz;
    inv_rigid(dq, dt, b, i00, i01, i02, i10, i11, i12, i20, i21, i22, tix, tiy, tiz);

    // Fused tiny batch_T_pred = delta_T_inv @ T_mis (16 floats per batch)
    if (blockIdx.x == 0 && threadIdx.x < 16) {
        int i = threadIdx.x >> 2, k = threadIdx.x & 3;
        const float* T = T_mis + b * 16;
        float val;
        if (i == 0)      val = i00 * T[k] + i01 * T[4 + k] + i02 * T[8 + k] + tix * T[12 + k];
        else if (i == 1) val = i10 * T[k] + i11 * T[4 + k] + i12 * T[8 + k] + tiy * T[12 + k];
        else if (i == 2) val = i20 * T[k] + i21 * T[4 + k] + i22 * T[8 + k] + tiz * T[12 + k];
        else             val = T[12 + k];
        out_T[b * 16 + threadIdx.x] = val;
    }

    int m = blockIdx.x * blockDim.x + threadIdx.x;  // float4 index within batch
    long long base = (long long)b * m4_per_batch;
    bool active = (m < m4_per_batch);

    float4 v = active ? pin[base + m] : make_float4(0.f, 0.f, 0.f, 0.f);

    int lane = threadIdx.x & 63;
    int r = m % 3;

    // neighbor components via wave shuffles (width 64)
    float sz = __shfl_up(v.z, 1);   // in[m-1].z
    float sw = __shfl_up(v.w, 1);   // in[m-1].w
    float sx = __shfl_down(v.x, 1); // in[m+1].x
    float sy = __shfl_down(v.y, 1); // in[m+1].y

    // wave-edge fixups (batch edges never need the missing side: edge m%3
    // cases 0/2 don't use m-1/m+1 respectively)
    if (active && lane == 0 && r != 0) {
        float2 t2 = *(const float2*)((const float*)(pin + base + m - 1) + 2);
        sz = t2.x; sw = t2.y;
    }
    if (active && lane == 63 && r != 2) {
        float2 t2 = *(const float2*)((const float*)(pin + base + m + 1));
        sx = t2.x; sy = t2.y;
    }

    float4 o;
    if (r == 0) {
        o.x = i00 * v.x + i01 * v.y + i02 * v.z + tix;
        o.y = i10 * v.x + i11 * v.y + i12 * v.z + tiy;
        o.z = i20 * v.x + i21 * v.y + i22 * v.z + tiz;
        o.w = i00 * v.w + i01 * sx  + i02 * sy  + tix;
    } else if (r == 1) {
        o.x = i10 * sw  + i11 * v.x + i12 * v.y + tiy;
        o.y = i20 * sw  + i21 * v.x + i22 * v.y + tiz;
        o.z = i00 * v.z + i01 * v.w + i02 * sx  + tix;
        o.w = i10 * v.z + i11 * v.w + i12 * sx  + tiy;
    } else {
        o.x = i20 * sz  + i21 * sw  + i22 * v.x + tiz;
        o.y = i00 * v.y + i01 * v.z + i02 * v.w + tix;
        o.z = i10 * v.y + i11 * v.z + i12 * v.w + tiy;
        o.w = i20 * v.y + i21 * v.z + i22 * v.w + tiz;
    }

    if (active) pout[base + m] = o;
}

// Scalar fallback (only used if N*3 % 4 != 0 — not the case here).
__global__ void realign_scalar_kernel(const float* __restrict__ pin,
                                      float* __restrict__ pout,
                                      const float* __restrict__ dq,
                                      const float* __restrict__ dt,
                                      long long n_per_batch) {
    int b = blockIdx.y;
    float i00, i01, i02, i10, i11, i12, i20, i21, i22, tix, tiy, tiz;
    inv_rigid(dq, dt, b, i00, i01, i02, i10, i11, i12, i20, i21, i22, tix, tiy, tiz);
    long long base = (long long)b * n_per_batch * 3LL;
    for (long long p = (long long)blockIdx.x * blockDim.x + threadIdx.x;
         p < n_per_batch; p += (long long)gridDim.x * blockDim.x) {
        float x = pin[base + p * 3 + 0];
        float y = pin[base + p * 3 + 1];
        float z = pin[base + p * 3 + 2];
        pout[base + p * 3 + 0] = i00 * x + i01 * y + i02 * z + tix;
        pout[base + p * 3 + 1] = i10 * x + i11 * y + i12 * z + tiy;
        pout[base + p * 3 + 2] = i20 * x + i21 * y + i22 * z + tiz;
    }
}

__global__ void batch_T_kernel(const float* __restrict__ T_mis,
                               const float* __restrict__ dq,
                               const float* __restrict__ dt,
                               float* __restrict__ out_T, int B) {
    int b = threadIdx.x;
    if (b >= B) return;
    float i00, i01, i02, i10, i11, i12, i20, i21, i22, tix, tiy, tiz;
    inv_rigid(dq, dt, b, i00, i01, i02, i10, i11, i12, i20, i21, i22, tix, tiy, tiz);
    const float* T = T_mis + b * 16;
    float* O = out_T + b * 16;
    float Ri[3][3] = {{i00, i01, i02}, {i10, i11, i12}, {i20, i21, i22}};
    float ti[3] = {tix, tiy, tiz};
#pragma unroll
    for (int i = 0; i < 3; ++i)
#pragma unroll
        for (int k = 0; k < 4; ++k)
            O[i * 4 + k] = Ri[i][0] * T[k] + Ri[i][1] * T[4 + k] +
                           Ri[i][2] * T[8 + k] + ti[i] * T[12 + k];
#pragma unroll
    for (int k = 0; k < 4; ++k) O[12 + k] = T[12 + k];
}

extern "C" void kernel_launch(void* const* d_in, const int* in_sizes, int n_in,
                              void* d_out, int out_size, void* d_ws, size_t ws_size,
                              hipStream_t stream) {
    const float* pcd = (const float*)d_in[0];      // (B, N, 3)
    const float* T_mis = (const float*)d_in[1];    // (B, 4, 4)
    const float* dq = (const float*)d_in[2];       // (B, 4)
    const float* dt = (const float*)d_in[3];       // (B, 3)

    int B = in_sizes[2] / 4;                           // 16
    long long N = (long long)in_sizes[0] / (3LL * B);  // 500000
    long long nf = N * 3LL;                            // floats per batch

    float* out_T = (float*)d_out;                       // first B*16 floats
    float* out_pcd = (float*)d_out + (long long)B * 16; // then B*N*3 floats

    if ((nf & 3LL) == 0LL) {
        int m4 = (int)(nf >> 2);                       // float4s per batch
        int blocks_x = (m4 + 255) / 256;
        dim3 grid(blocks_x, B);
        realign_kernel<<<grid, dim3(256), 0, stream>>>(
            (const float4*)pcd, (float4*)out_pcd, T_mis, dq, dt, out_T, m4);
    } else {
        batch_T_kernel<<<dim3(1), dim3(64), 0, stream>>>(T_mis, dq, dt, out_T, B);
        int blocks_x = (int)((N + 255) / 256);
        if (blocks_x > 4096) blocks_x = 4096;
        dim3 grid(blocks_x, B);
        realign_scalar_kernel<<<grid, dim3(256), 0, stream>>>(
            pcd, out_pcd, dq, dt, N);
    }
}

// Round 3
// 35.091 us; speedup vs baseline: 1.1797x; 1.1329x over previous
//
#include <hip/hip_runtime.h>

typedef float f4_native __attribute__((ext_vector_type(4)));

// Compute the 12 constants of the inverse rigid transform for batch b:
//   R = quat_to_rot(normalize(q));  Rinv = R^T;  tinv = -R^T * t
__device__ __forceinline__ void inv_rigid(const float* __restrict__ dq,
                                          const float* __restrict__ dt,
                                          int b,
                                          float& i00, float& i01, float& i02,
                                          float& i10, float& i11, float& i12,
                                          float& i20, float& i21, float& i22,
                                          float& tix, float& tiy, float& tiz) {
    float qw = dq[b * 4 + 0];
    float qx = dq[b * 4 + 1];
    float qy = dq[b * 4 + 2];
    float qz = dq[b * 4 + 3];
    float inv = 1.0f / sqrtf(qw * qw + qx * qx + qy * qy + qz * qz);
    qw *= inv; qx *= inv; qy *= inv; qz *= inv;

    float r00 = 1.0f - 2.0f * (qy * qy + qz * qz);
    float r01 = 2.0f * (qx * qy - qw * qz);
    float r02 = 2.0f * (qx * qz + qw * qy);
    float r10 = 2.0f * (qx * qy + qw * qz);
    float r11 = 1.0f - 2.0f * (qx * qx + qz * qz);
    float r12 = 2.0f * (qy * qz - qw * qx);
    float r20 = 2.0f * (qx * qz - qw * qy);
    float r21 = 2.0f * (qy * qz + qw * qx);
    float r22 = 1.0f - 2.0f * (qx * qx + qy * qy);

    // Rinv = R^T
    i00 = r00; i01 = r10; i02 = r20;
    i10 = r01; i11 = r11; i12 = r21;
    i20 = r02; i21 = r12; i22 = r22;

    float tx = dt[b * 3 + 0];
    float ty = dt[b * 3 + 1];
    float tz = dt[b * 3 + 2];
    tix = -(i00 * tx + i01 * ty + i02 * tz);
    tiy = -(i10 * tx + i11 * ty + i12 * tz);
    tiz = -(i20 * tx + i21 * ty + i22 * tz);
}

#define ITERS 4

// Fully-coalesced point transform. Each wave owns ITERS contiguous slots of 64
// float4s; each thread holds one float4 per slot -> 4 unit-stride 1024B loads
// in flight per wave, inv_rigid amortized 4x. Neighbor xyz components come
// from __shfl within a slot; slot-boundary lanes patch from the adjacent
// slot's register via broadcast shuffles; only the wave's outermost edges
// (slot 0 lane 0 / slot ITERS-1 lane 63) fall back to a tiny float2 load.
//
// Output float4 m covers global floats 4m..4m+3; with r = m%3:
//   r==0: p0=(v.x,v.y,v.z), p1=(v.w, in[m+1].x, in[m+1].y)
//   r==1: p1=(in[m-1].w, v.x, v.y), p2=(v.z, v.w, in[m+1].x)
//   r==2: p2=(in[m-1].z, in[m-1].w, v.x), p3=(v.y,v.z,v.w)
// Note: float4 path is only taken when N%4==0, which implies the last float4
// of each batch has r==2 -> the m+1 patch never reads past the batch.
__global__ void realign_kernel(const float4* __restrict__ pin,
                               float4* __restrict__ pout,
                               const float* __restrict__ T_mis,
                               const float* __restrict__ dq,
                               const float* __restrict__ dt,
                               float* __restrict__ out_T,
                               int m4_per_batch)  // = N*3/4 float4s per batch
{
    int b = blockIdx.y;

    float i00, i01, i02, i10, i11, i12, i20, i21, i22, tix, tiy, tiz;
    inv_rigid(dq, dt, b, i00, i01, i02, i10, i11, i12, i20, i21, i22, tix, tiy, tiz);

    // Fused tiny batch_T_pred = delta_T_inv @ T_mis (16 floats per batch)
    if (blockIdx.x == 0 && threadIdx.x < 16) {
        int i = threadIdx.x >> 2, k = threadIdx.x & 3;
        const float* T = T_mis + b * 16;
        float val;
        if (i == 0)      val = i00 * T[k] + i01 * T[4 + k] + i02 * T[8 + k] + tix * T[12 + k];
        else if (i == 1) val = i10 * T[k] + i11 * T[4 + k] + i12 * T[8 + k] + tiy * T[12 + k];
        else if (i == 2) val = i20 * T[k] + i21 * T[4 + k] + i22 * T[8 + k] + tiz * T[12 + k];
        else             val = T[12 + k];
        out_T[b * 16 + threadIdx.x] = val;
    }

    int lane = threadIdx.x & 63;
    int wave = threadIdx.x >> 6;
    // block chunk = blockDim.x * ITERS float4s; wave chunk = 64*ITERS
    int wbase = blockIdx.x * (blockDim.x * ITERS) + wave * (64 * ITERS) + lane;
    long long base = (long long)b * m4_per_batch;

    float4 v[ITERS];
    bool act[ITERS];
#pragma unroll
    for (int j = 0; j < ITERS; ++j) {
        int m = wbase + 64 * j;
        act[j] = (m < m4_per_batch);
        v[j] = act[j] ? pin[base + m] : make_float4(0.f, 0.f, 0.f, 0.f);
    }

#pragma unroll
    for (int j = 0; j < ITERS; ++j) {
        int m = wbase + 64 * j;
        int r = m % 3;

        // neighbor components within the slot
        float sz = __shfl_up(v[j].z, 1);   // in[m-1].z
        float sw = __shfl_up(v[j].w, 1);   // in[m-1].w
        float sx = __shfl_down(v[j].x, 1); // in[m+1].x
        float sy = __shfl_down(v[j].y, 1); // in[m+1].y

        // slot-boundary patches from adjacent slot registers (convergent shuffles)
        if (j > 0) {
            float pz = __shfl(v[j - 1].z, 63);
            float pw = __shfl(v[j - 1].w, 63);
            if (lane == 0) { sz = pz; sw = pw; }
        }
        if (j < ITERS - 1) {
            float nx = __shfl(v[j + 1].x, 0);
            float ny = __shfl(v[j + 1].y, 0);
            if (lane == 63) { sx = nx; sy = ny; }
        }
        // wave-outermost edges: tiny global patch loads (L2-hit)
        if (j == 0 && lane == 0 && act[0] && r != 0) {
            float2 t2 = *(const float2*)((const float*)(pin + base + m - 1) + 2);
            sz = t2.x; sw = t2.y;
        }
        if (j == ITERS - 1 && lane == 63 && act[j] && r != 2) {
            float2 t2 = *(const float2*)((const float*)(pin + base + m + 1));
            sx = t2.x; sy = t2.y;
        }

        float4 o;
        if (r == 0) {
            o.x = i00 * v[j].x + i01 * v[j].y + i02 * v[j].z + tix;
            o.y = i10 * v[j].x + i11 * v[j].y + i12 * v[j].z + tiy;
            o.z = i20 * v[j].x + i21 * v[j].y + i22 * v[j].z + tiz;
            o.w = i00 * v[j].w + i01 * sx     + i02 * sy     + tix;
        } else if (r == 1) {
            o.x = i10 * sw     + i11 * v[j].x + i12 * v[j].y + tiy;
            o.y = i20 * sw     + i21 * v[j].x + i22 * v[j].y + tiz;
            o.z = i00 * v[j].z + i01 * v[j].w + i02 * sx     + tix;
            o.w = i10 * v[j].z + i11 * v[j].w + i12 * sx     + tiy;
        } else {
            o.x = i20 * sz     + i21 * sw     + i22 * v[j].x + tiz;
            o.y = i00 * v[j].y + i01 * v[j].z + i02 * v[j].w + tix;
            o.z = i10 * v[j].y + i11 * v[j].z + i12 * v[j].w + tiy;
            o.w = i20 * v[j].y + i21 * v[j].z + i22 * v[j].w + tiz;
        }

        if (act[j]) {
            // nontemporal: keep the 96MB write stream out of L2/L3 so the
            // input stays cache-resident
            __builtin_nontemporal_store(*(const f4_native*)&o,
                                        (f4_native*)(pout + base + m));
        }
    }
}

// Scalar fallback (only used if N*3 % 4 != 0 — not the case here).
__global__ void realign_scalar_kernel(const float* __restrict__ pin,
                                      float* __restrict__ pout,
                                      const float* __restrict__ dq,
                                      const float* __restrict__ dt,
                                      long long n_per_batch) {
    int b = blockIdx.y;
    float i00, i01, i02, i10, i11, i12, i20, i21, i22, tix, tiy, tiz;
    inv_rigid(dq, dt, b, i00, i01, i02, i10, i11, i12, i20, i21, i22, tix, tiy, tiz);
    long long base = (long long)b * n_per_batch * 3LL;
    for (long long p = (long long)blockIdx.x * blockDim.x + threadIdx.x;
         p < n_per_batch; p += (long long)gridDim.x * blockDim.x) {
        float x = pin[base + p * 3 + 0];
        float y = pin[base + p * 3 + 1];
        float z = pin[base + p * 3 + 2];
        pout[base + p * 3 + 0] = i00 * x + i01 * y + i02 * z + tix;
        pout[base + p * 3 + 1] = i10 * x + i11 * y + i12 * z + tiy;
        pout[base + p * 3 + 2] = i20 * x + i21 * y + i22 * z + tiz;
    }
}

__global__ void batch_T_kernel(const float* __restrict__ T_mis,
                               const float* __restrict__ dq,
                               const float* __restrict__ dt,
                               float* __restrict__ out_T, int B) {
    int b = threadIdx.x;
    if (b >= B) return;
    float i00, i01, i02, i10, i11, i12, i20, i21, i22, tix, tiy, tiz;
    inv_rigid(dq, dt, b, i00, i01, i02, i10, i11, i12, i20, i21, i22, tix, tiy, tiz);
    const float* T = T_mis + b * 16;
    float* O = out_T + b * 16;
    float Ri[3][3] = {{i00, i01, i02}, {i10, i11, i12}, {i20, i21, i22}};
    float ti[3] = {tix, tiy, tiz};
#pragma unroll
    for (int i = 0; i < 3; ++i)
#pragma unroll
        for (int k = 0; k < 4; ++k)
            O[i * 4 + k] = Ri[i][0] * T[k] + Ri[i][1] * T[4 + k] +
                           Ri[i][2] * T[8 + k] + ti[i] * T[12 + k];
#pragma unroll
    for (int k = 0; k < 4; ++k) O[12 + k] = T[12 + k];
}

extern "C" void kernel_launch(void* const* d_in, const int* in_sizes, int n_in,
                              void* d_out, int out_size, void* d_ws, size_t ws_size,
                              hipStream_t stream) {
    const float* pcd = (const float*)d_in[0];      // (B, N, 3)
    const float* T_mis = (const float*)d_in[1];    // (B, 4, 4)
    const float* dq = (const float*)d_in[2];       // (B, 4)
    const float* dt = (const float*)d_in[3];       // (B, 3)

    int B = in_sizes[2] / 4;                           // 16
    long long N = (long long)in_sizes[0] / (3LL * B);  // 500000
    long long nf = N * 3LL;                            // floats per batch

    float* out_T = (float*)d_out;                       // first B*16 floats
    float* out_pcd = (float*)d_out + (long long)B * 16; // then B*N*3 floats

    if ((nf & 3LL) == 0LL) {
        int m4 = (int)(nf >> 2);                       // float4s per batch
        int per_block = 256 * ITERS;
        int blocks_x = (m4 + per_block - 1) / per_block;
        dim3 grid(blocks_x, B);
        realign_kernel<<<grid, dim3(256), 0, stream>>>(
            (const float4*)pcd, (float4*)out_pcd, T_mis, dq, dt, out_T, m4);
    } else {
        batch_T_kernel<<<dim3(1), dim3(64), 0, stream>>>(T_mis, dq, dt, out_T, B);
        int blocks_x = (int)((N + 255) / 256);
        if (blocks_x > 4096) blocks_x = 4096;
        dim3 grid(blocks_x, B);
        realign_scalar_kernel<<<grid, dim3(256), 0, stream>>>(
            pcd, out_pcd, dq, dt, N);
    }
}